// Round 1
// baseline (253.114 us; speedup 1.0000x reference)
//
#include <hip/hip_runtime.h>
#include <hip/hip_bf16.h>

#define DIM 1024
#define HEADS 16
#define DH 64
#define SEQ 2048
#define BATCH 2
#define ROWS (BATCH*SEQ)
#define C3 (3*DIM)

typedef __attribute__((ext_vector_type(8))) short s16x8;
typedef __attribute__((ext_vector_type(4))) float f32x4;

__device__ __forceinline__ void gll16(const void* g, void* l) {
  __builtin_amdgcn_global_load_lds((const __attribute__((address_space(1))) void*)g,
                                   (__attribute__((address_space(3))) void*)l, 16, 0, 0);
}

// ---------------- LayerNorm: x[4096][1024] f32 -> xn bf16 ----------------
__global__ __launch_bounds__(256) void ln_kernel(const float* __restrict__ x,
    const float* __restrict__ gamma, const float* __restrict__ beta,
    __hip_bfloat16* __restrict__ xn) {
  int row = blockIdx.x;
  int t = threadIdx.x;
  const float4* xp = (const float4*)(x + (size_t)row * DIM);
  float4 v = xp[t];
  float s = v.x + v.y + v.z + v.w;
  float q = v.x*v.x + v.y*v.y + v.z*v.z + v.w*v.w;
  for (int off = 32; off >= 1; off >>= 1) {
    s += __shfl_xor(s, off, 64);
    q += __shfl_xor(q, off, 64);
  }
  __shared__ float red[8];
  int w = t >> 6;
  if ((t & 63) == 0) { red[w] = s; red[4 + w] = q; }
  __syncthreads();
  s = red[0] + red[1] + red[2] + red[3];
  q = red[4] + red[5] + red[6] + red[7];
  float mu = s * (1.0f / DIM);
  float var = q * (1.0f / DIM) - mu * mu;
  float rstd = rsqrtf(var + 1e-5f);
  int c = t * 4;
  float4 g4 = ((const float4*)gamma)[t];
  float4 b4 = ((const float4*)beta)[t];
  __hip_bfloat16* op = xn + (size_t)row * DIM + c;
  op[0] = __float2bfloat16((v.x - mu) * rstd * g4.x + b4.x);
  op[1] = __float2bfloat16((v.y - mu) * rstd * g4.y + b4.y);
  op[2] = __float2bfloat16((v.z - mu) * rstd * g4.z + b4.z);
  op[3] = __float2bfloat16((v.w - mu) * rstd * g4.w + b4.w);
}

// ---------------- Transpose + convert: in f32 [R][Cn] -> out bf16 [Cn][R] ----------------
__global__ __launch_bounds__(256) void transpose_cvt(const float* __restrict__ in,
    __hip_bfloat16* __restrict__ out, int R, int Cn) {
  __shared__ float tile[32][33];
  int c0 = blockIdx.x * 32, r0 = blockIdx.y * 32;
  int tx = threadIdx.x & 31, ty = threadIdx.x >> 5;  // 32 x 8
#pragma unroll
  for (int i = 0; i < 4; i++)
    tile[ty + i * 8][tx] = in[(size_t)(r0 + ty + i * 8) * Cn + c0 + tx];
  __syncthreads();
#pragma unroll
  for (int i = 0; i < 4; i++)
    out[(size_t)(c0 + ty + i * 8) * R + r0 + tx] = __float2bfloat16(tile[tx][ty + i * 8]);
}

// ---------------- GEMM: C[M][Nc] = A[M][K](bf16) * Bt[Nc][K](bf16)^T ----------------
// 128x128 tile, 4 waves (2x2), BK=32, global_load_lds staging.
template<int WITH_BIAS>
__global__ __launch_bounds__(256) void gemm_bt(const __hip_bfloat16* __restrict__ A,
    const __hip_bfloat16* __restrict__ Bt, void* __restrict__ Cptr,
    const float* __restrict__ bias, int M, int Nc, int K) {
  __shared__ short lds_a[128 * 32];
  __shared__ short lds_b[128 * 32];
  int t = threadIdx.x;
  int l = t & 63, w = t >> 6;
  int wr = w >> 1, wc = w & 1;
  int m0 = blockIdx.y * 128, n0 = blockIdx.x * 128;
  f32x4 acc[4][4] = {};
  const short* Ab = (const short*)A;
  const short* Bb = (const short*)Bt;
  int srow = t >> 2;            // 0..63 (row within 64-row pass)
  int scol = (t & 3) * 8;       // element col within BK=32
  char* la = (char*)lds_a + (t >> 6) * 1024;
  char* lb = (char*)lds_b + (t >> 6) * 1024;
  for (int kk = 0; kk < K; kk += 32) {
    gll16(Ab + (size_t)(m0 + srow) * K + kk + scol,      la);
    gll16(Ab + (size_t)(m0 + 64 + srow) * K + kk + scol, la + 4096);
    gll16(Bb + (size_t)(n0 + srow) * K + kk + scol,      lb);
    gll16(Bb + (size_t)(n0 + 64 + srow) * K + kk + scol, lb + 4096);
    asm volatile("s_waitcnt vmcnt(0)" ::: "memory");
    __syncthreads();
    s16x8 af[4], bf[4];
#pragma unroll
    for (int m = 0; m < 4; m++)
      af[m] = *(const s16x8*)&lds_a[(wr * 64 + m * 16 + (l & 15)) * 32 + (l >> 4) * 8];
#pragma unroll
    for (int n = 0; n < 4; n++)
      bf[n] = *(const s16x8*)&lds_b[(wc * 64 + n * 16 + (l & 15)) * 32 + (l >> 4) * 8];
#pragma unroll
    for (int m = 0; m < 4; m++)
#pragma unroll
      for (int n = 0; n < 4; n++)
        acc[m][n] = __builtin_amdgcn_mfma_f32_16x16x32_bf16(af[m], bf[n], acc[m][n], 0, 0, 0);
    __syncthreads();
  }
  if (WITH_BIAS) {
    float* C = (float*)Cptr;
#pragma unroll
    for (int m = 0; m < 4; m++)
#pragma unroll
      for (int n = 0; n < 4; n++) {
        int col = n0 + wc * 64 + n * 16 + (l & 15);
        float bb = bias[col];
#pragma unroll
        for (int r = 0; r < 4; r++) {
          int row = m0 + wr * 64 + m * 16 + (l >> 4) * 4 + r;
          C[(size_t)row * Nc + col] = acc[m][n][r] + bb;
        }
      }
  } else {
    __hip_bfloat16* C = (__hip_bfloat16*)Cptr;
#pragma unroll
    for (int m = 0; m < 4; m++)
#pragma unroll
      for (int n = 0; n < 4; n++) {
        int col = n0 + wc * 64 + n * 16 + (l & 15);
#pragma unroll
        for (int r = 0; r < 4; r++) {
          int row = m0 + wr * 64 + m * 16 + (l >> 4) * 4 + r;
          C[(size_t)row * Nc + col] = __float2bfloat16(acc[m][n][r]);
        }
      }
  }
}

// ---------------- Flash attention ----------------
// qkv bf16 [4096][3072] (q|k|v each [..][h*64+d]); out attno bf16 [4096][1024].
// Block: 256 threads = 4 waves; 128 Q rows per block (32/wave); KV tile 64.
__global__ __launch_bounds__(256) void attn_kernel(const __hip_bfloat16* __restrict__ qkv,
    __hip_bfloat16* __restrict__ attno) {
  int t = threadIdx.x, l = t & 63, w = t >> 6;
  int qb = blockIdx.x;           // 0..15
  int bh = blockIdx.y;           // 0..31
  int b = bh >> 4, h = bh & 15;
  const short* base = (const short*)qkv + (size_t)b * SEQ * C3 + h * DH;
  int qr0 = qb * 128 + w * 32;
  // Q fragments, hoisted (rows qr0..qr0+31, d 0..63)
  s16x8 qf[2][2];
#pragma unroll
  for (int m = 0; m < 2; m++)
#pragma unroll
    for (int ks = 0; ks < 2; ks++)
      qf[m][ks] = *(const s16x8*)(base + (size_t)(qr0 + m * 16 + (l & 15)) * C3 + ks * 32 + (l >> 4) * 8);

  __shared__ short kt[64 * 64];      // K tile [kv][d]
  __shared__ short vt[64 * 64];      // V^T tile [d][kv]
  __shared__ short pt[4][32 * 64];   // per-wave P [32 q][64 kv]
  f32x4 o[2][4] = {};
  float mrun[2][4], lrun[2][4];
#pragma unroll
  for (int m = 0; m < 2; m++)
#pragma unroll
    for (int r = 0; r < 4; r++) { mrun[m][r] = -1e30f; lrun[m][r] = 0.f; }

  const short* kbase = base + DIM;
  const short* vbase = base + 2 * DIM;
  char* lk = (char*)kt + w * 1024;
  int krow = t >> 3;            // 0..31
  int kcol = (t & 7) * 8;       // 0..56
  __hip_bfloat16* ptw = (__hip_bfloat16*)&pt[w][0];

  for (int tile = 0; tile < SEQ / 64; ++tile) {
    int kv0 = tile * 64;
    // stage K [64][64] via global_load_lds (2 passes of 32 rows)
    gll16(kbase + (size_t)(kv0 + krow) * C3 + kcol,      lk);
    gll16(kbase + (size_t)(kv0 + 32 + krow) * C3 + kcol, lk + 4096);
    // stage V transposed: read [kv][d] 16B chunks, scatter to vt[d][kv]
    {
      s16x8 v8a = *(const s16x8*)(vbase + (size_t)(kv0 + krow) * C3 + kcol);
      s16x8 v8b = *(const s16x8*)(vbase + (size_t)(kv0 + 32 + krow) * C3 + kcol);
#pragma unroll
      for (int i = 0; i < 8; i++) {
        vt[(kcol + i) * 64 + krow] = v8a[i];
        vt[(kcol + i) * 64 + 32 + krow] = v8b[i];
      }
    }
    asm volatile("s_waitcnt vmcnt(0)" ::: "memory");
    __syncthreads();
    // S = Q K^T (32x64 per wave)
    f32x4 s[2][4] = {};
#pragma unroll
    for (int ks = 0; ks < 2; ++ks) {
      s16x8 kf[4];
#pragma unroll
      for (int n = 0; n < 4; n++)
        kf[n] = *(const s16x8*)&kt[(n * 16 + (l & 15)) * 64 + ks * 32 + (l >> 4) * 8];
#pragma unroll
      for (int m = 0; m < 2; m++)
#pragma unroll
        for (int n = 0; n < 4; n++)
          s[m][n] = __builtin_amdgcn_mfma_f32_16x16x32_bf16(qf[m][ks], kf[n], s[m][n], 0, 0, 0);
    }
    // online softmax (each lane owns rows (m, (l>>4)*4+r), cols n*16+(l&15))
#pragma unroll
    for (int m = 0; m < 2; m++) {
#pragma unroll
      for (int r = 0; r < 4; r++) {
        float mx = -1e30f;
#pragma unroll
        for (int n = 0; n < 4; n++) { s[m][n][r] *= 0.125f; mx = fmaxf(mx, s[m][n][r]); }
        for (int off = 1; off < 16; off <<= 1) mx = fmaxf(mx, __shfl_xor(mx, off, 64));
        float mo = mrun[m][r];
        float mn = fmaxf(mo, mx);
        float alpha = __expf(mo - mn);
        float rs = 0.f;
#pragma unroll
        for (int n = 0; n < 4; n++) { float p = __expf(s[m][n][r] - mn); s[m][n][r] = p; rs += p; }
        for (int off = 1; off < 16; off <<= 1) rs += __shfl_xor(rs, off, 64);
        lrun[m][r] = lrun[m][r] * alpha + rs;
        mrun[m][r] = mn;
#pragma unroll
        for (int d = 0; d < 4; d++) o[m][d][r] *= alpha;
      }
    }
    // write P to per-wave LDS (bf16)
#pragma unroll
    for (int m = 0; m < 2; m++)
#pragma unroll
      for (int n = 0; n < 4; n++)
#pragma unroll
        for (int r = 0; r < 4; r++)
          ptw[(m * 16 + (l >> 4) * 4 + r) * 64 + n * 16 + (l & 15)] = __float2bfloat16(s[m][n][r]);
    __syncthreads();
    // O += P V
#pragma unroll
    for (int ks = 0; ks < 2; ks++) {
      s16x8 pa[2], vf[4];
#pragma unroll
      for (int m = 0; m < 2; m++)
        pa[m] = *(const s16x8*)&pt[w][(m * 16 + (l & 15)) * 64 + ks * 32 + (l >> 4) * 8];
#pragma unroll
      for (int d = 0; d < 4; d++)
        vf[d] = *(const s16x8*)&vt[(d * 16 + (l & 15)) * 64 + ks * 32 + (l >> 4) * 8];
#pragma unroll
      for (int m = 0; m < 2; m++)
#pragma unroll
        for (int d = 0; d < 4; d++)
          o[m][d] = __builtin_amdgcn_mfma_f32_16x16x32_bf16(pa[m], vf[d], o[m][d], 0, 0, 0);
    }
    __syncthreads();
  }
  // epilogue: normalize and store
  int qrow_b = b * SEQ + qr0;
#pragma unroll
  for (int m = 0; m < 2; m++)
#pragma unroll
    for (int d = 0; d < 4; d++) {
      int col = h * DH + d * 16 + (l & 15);
#pragma unroll
      for (int r = 0; r < 4; r++) {
        float inv = 1.0f / lrun[m][r];
        attno[(size_t)(qrow_b + m * 16 + (l >> 4) * 4 + r) * DIM + col] =
            __float2bfloat16(o[m][d][r] * inv);
      }
    }
}

extern "C" void kernel_launch(void* const* d_in, const int* in_sizes, int n_in,
                              void* d_out, int out_size, void* d_ws, size_t ws_size,
                              hipStream_t stream) {
  const float* x     = (const float*)d_in[0];
  const float* gamma = (const float*)d_in[1];
  const float* beta  = (const float*)d_in[2];
  const float* Wqkv  = (const float*)d_in[3];
  const float* Wout  = (const float*)d_in[4];
  const float* bout  = (const float*)d_in[5];

  __hip_bfloat16* xn     = (__hip_bfloat16*)d_ws;
  __hip_bfloat16* wqkv_t = xn + (size_t)ROWS * DIM;        // [3072][1024]
  __hip_bfloat16* wout_t = wqkv_t + (size_t)C3 * DIM;      // [1024][1024]
  __hip_bfloat16* qkv    = wout_t + (size_t)DIM * DIM;     // [4096][3072]
  __hip_bfloat16* attno  = qkv + (size_t)ROWS * C3;        // [4096][1024]

  ln_kernel<<<ROWS, 256, 0, stream>>>(x, gamma, beta, xn);
  transpose_cvt<<<dim3(C3 / 32, DIM / 32), 256, 0, stream>>>(Wqkv, wqkv_t, DIM, C3);
  transpose_cvt<<<dim3(DIM / 32, DIM / 32), 256, 0, stream>>>(Wout, wout_t, DIM, DIM);
  gemm_bt<0><<<dim3(C3 / 128, ROWS / 128), 256, 0, stream>>>(xn, wqkv_t, (void*)qkv, nullptr, ROWS, C3, DIM);
  attn_kernel<<<dim3(SEQ / 128, BATCH * HEADS), 256, 0, stream>>>(qkv, attno);
  gemm_bt<1><<<dim3(DIM / 128, ROWS / 128), 256, 0, stream>>>(attno, wout_t, d_out, bout, ROWS, DIM, DIM);
}

// Round 2
// 154.447 us; speedup vs baseline: 1.6388x; 1.6388x over previous
//
#include <hip/hip_runtime.h>
#include <hip/hip_bf16.h>

#define DIM 1024
#define HEADS 16
#define DH 64
#define SEQ 2048
#define BATCH 2
#define ROWS (BATCH*SEQ)
#define C3 (3*DIM)

typedef __attribute__((ext_vector_type(8))) short s16x8;
typedef __attribute__((ext_vector_type(4))) float f32x4;
typedef __attribute__((ext_vector_type(16))) float f32x16;
typedef __attribute__((ext_vector_type(4))) unsigned int u32x4;

__device__ __forceinline__ void gll16(const void* g, void* l) {
  __builtin_amdgcn_global_load_lds((const __attribute__((address_space(1))) void*)g,
                                   (__attribute__((address_space(3))) void*)l, 16, 0, 0);
}
__device__ __forceinline__ float bf2f(short s) {
  return __builtin_bit_cast(float, ((unsigned)(unsigned short)s) << 16);
}
__device__ __forceinline__ short f2bf(float f) {
  return (short)__bfloat16_as_ushort(__float2bfloat16(f));
}
__device__ __forceinline__ unsigned pk2(float a, float b) {
  unsigned lo = (unsigned)__bfloat16_as_ushort(__float2bfloat16(a));
  unsigned hh = (unsigned)__bfloat16_as_ushort(__float2bfloat16(b));
  return lo | (hh << 16);
}

// ---------------- LayerNorm: x[4096][1024] f32 -> xn bf16 ----------------
__global__ __launch_bounds__(256) void ln_kernel(const float* __restrict__ x,
    const float* __restrict__ gamma, const float* __restrict__ beta,
    __hip_bfloat16* __restrict__ xn) {
  int row = blockIdx.x;
  int t = threadIdx.x;
  const float4* xp = (const float4*)(x + (size_t)row * DIM);
  float4 v = xp[t];
  float s = v.x + v.y + v.z + v.w;
  float q = v.x*v.x + v.y*v.y + v.z*v.z + v.w*v.w;
  for (int off = 32; off >= 1; off >>= 1) {
    s += __shfl_xor(s, off, 64);
    q += __shfl_xor(q, off, 64);
  }
  __shared__ float red[8];
  int w = t >> 6;
  if ((t & 63) == 0) { red[w] = s; red[4 + w] = q; }
  __syncthreads();
  s = red[0] + red[1] + red[2] + red[3];
  q = red[4] + red[5] + red[6] + red[7];
  float mu = s * (1.0f / DIM);
  float var = q * (1.0f / DIM) - mu * mu;
  float rstd = rsqrtf(var + 1e-5f);
  int c = t * 4;
  float4 g4 = ((const float4*)gamma)[t];
  float4 b4 = ((const float4*)beta)[t];
  __hip_bfloat16* op = xn + (size_t)row * DIM + c;
  op[0] = __float2bfloat16((v.x - mu) * rstd * g4.x + b4.x);
  op[1] = __float2bfloat16((v.y - mu) * rstd * g4.y + b4.y);
  op[2] = __float2bfloat16((v.z - mu) * rstd * g4.z + b4.z);
  op[3] = __float2bfloat16((v.w - mu) * rstd * g4.w + b4.w);
}

// ---------------- Transpose + convert: in f32 [R][Cn] -> out bf16 [Cn][R] ----------------
__global__ __launch_bounds__(256) void transpose_cvt(const float* __restrict__ in,
    __hip_bfloat16* __restrict__ out, int R, int Cn) {
  __shared__ float tile[32][33];
  int c0 = blockIdx.x * 32, r0 = blockIdx.y * 32;
  int tx = threadIdx.x & 31, ty = threadIdx.x >> 5;  // 32 x 8
#pragma unroll
  for (int i = 0; i < 4; i++)
    tile[ty + i * 8][tx] = in[(size_t)(r0 + ty + i * 8) * Cn + c0 + tx];
  __syncthreads();
#pragma unroll
  for (int i = 0; i < 4; i++)
    out[(size_t)(c0 + ty + i * 8) * R + r0 + tx] = __float2bfloat16(tile[tx][ty + i * 8]);
}

// ---------------- GEMM: C[M][Nc] = A[M][K](bf16) * Bt[Nc][K](bf16)^T ----------------
template<int WITH_BIAS>
__global__ __launch_bounds__(256) void gemm_bt(const __hip_bfloat16* __restrict__ A,
    const __hip_bfloat16* __restrict__ Bt, void* __restrict__ Cptr,
    const float* __restrict__ bias, int M, int Nc, int K) {
  __shared__ short lds_a[128 * 32];
  __shared__ short lds_b[128 * 32];
  int t = threadIdx.x;
  int l = t & 63, w = t >> 6;
  int wr = w >> 1, wc = w & 1;
  int m0 = blockIdx.y * 128, n0 = blockIdx.x * 128;
  f32x4 acc[4][4] = {};
  const short* Ab = (const short*)A;
  const short* Bb = (const short*)Bt;
  int srow = t >> 2;
  int scol = (t & 3) * 8;
  char* la = (char*)lds_a + (t >> 6) * 1024;
  char* lb = (char*)lds_b + (t >> 6) * 1024;
  for (int kk = 0; kk < K; kk += 32) {
    gll16(Ab + (size_t)(m0 + srow) * K + kk + scol,      la);
    gll16(Ab + (size_t)(m0 + 64 + srow) * K + kk + scol, la + 4096);
    gll16(Bb + (size_t)(n0 + srow) * K + kk + scol,      lb);
    gll16(Bb + (size_t)(n0 + 64 + srow) * K + kk + scol, lb + 4096);
    asm volatile("s_waitcnt vmcnt(0)" ::: "memory");
    __syncthreads();
    s16x8 af[4], bf[4];
#pragma unroll
    for (int m = 0; m < 4; m++)
      af[m] = *(const s16x8*)&lds_a[(wr * 64 + m * 16 + (l & 15)) * 32 + (l >> 4) * 8];
#pragma unroll
    for (int n = 0; n < 4; n++)
      bf[n] = *(const s16x8*)&lds_b[(wc * 64 + n * 16 + (l & 15)) * 32 + (l >> 4) * 8];
#pragma unroll
    for (int m = 0; m < 4; m++)
#pragma unroll
      for (int n = 0; n < 4; n++)
        acc[m][n] = __builtin_amdgcn_mfma_f32_16x16x32_bf16(af[m], bf[n], acc[m][n], 0, 0, 0);
    __syncthreads();
  }
  if (WITH_BIAS) {
    float* C = (float*)Cptr;
#pragma unroll
    for (int m = 0; m < 4; m++)
#pragma unroll
      for (int n = 0; n < 4; n++) {
        int col = n0 + wc * 64 + n * 16 + (l & 15);
        float bb = bias[col];
#pragma unroll
        for (int r = 0; r < 4; r++) {
          int row = m0 + wr * 64 + m * 16 + (l >> 4) * 4 + r;
          C[(size_t)row * Nc + col] = acc[m][n][r] + bb;
        }
      }
  } else {
    __hip_bfloat16* C = (__hip_bfloat16*)Cptr;
#pragma unroll
    for (int m = 0; m < 4; m++)
#pragma unroll
      for (int n = 0; n < 4; n++) {
        int col = n0 + wc * 64 + n * 16 + (l & 15);
#pragma unroll
        for (int r = 0; r < 4; r++) {
          int row = m0 + wr * 64 + m * 16 + (l >> 4) * 4 + r;
          C[(size_t)row * Nc + col] = __float2bfloat16(acc[m][n][r]);
        }
      }
  }
}

// ---------------- Flash attention v2: swapped QK^T, in-register softmax ----------------
// 4 waves x 32 q-rows, KV tile 64, 32x32x16 MFMA, dbuf K/V in LDS.
// K: gll16 with pre-swizzled source (chunk ^= row&7); V^T: reg-staged packed
// dword writes, same swizzle; frag reads apply matching XOR -> ~conflict-free.
__global__ __launch_bounds__(256) void attn_kernel(const __hip_bfloat16* __restrict__ qkv,
    __hip_bfloat16* __restrict__ attno) {
  const int t = threadIdx.x, l = t & 63, w = t >> 6;
  const int hi = l >> 5, lq = l & 31;
  const int qb = blockIdx.x, bh = blockIdx.y;
  const int b = bh >> 4, h = bh & 15;
  const short* base  = (const short*)qkv + (size_t)b * SEQ * C3 + h * DH;
  const short* kbase = base + DIM;
  const short* vbase = base + 2 * DIM;
  const int qr0 = qb * 128 + w * 32;

  __shared__ short kbuf[2][64 * 64];
  __shared__ short vbuf[2][64 * 64];

  // Q fragments prescaled by 0.125 (exact in bf16: pow2)
  s16x8 qf[4];
#pragma unroll
  for (int dk = 0; dk < 4; dk++) {
    s16x8 raw = *(const s16x8*)(base + (size_t)(qr0 + lq) * C3 + dk * 16 + hi * 8);
#pragma unroll
    for (int j = 0; j < 8; j++) qf[dk][j] = f2bf(bf2f(raw[j]) * 0.125f);
  }

  f32x16 o0, o1;
#pragma unroll
  for (int r = 0; r < 16; r++) { o0[r] = 0.f; o1[r] = 0.f; }
  float m = -1e30f, lsum = 0.f;

  const int krow = t >> 3, kchk = t & 7;
  const int ksrc = kchk ^ (krow & 7);       // involution swizzle
  const int vr = t & 31, vc = (t >> 5) * 8; // V: kv-pair, d-chunk

  // prologue: stage tile 0 into buf 0
  {
    char* kd = (char*)&kbuf[0][0];
    gll16(kbase + (size_t)krow * C3 + ksrc * 8,        kd + t * 16);
    gll16(kbase + (size_t)(32 + krow) * C3 + ksrc * 8, kd + 4096 + t * 16);
    s16x8 va  = *(const s16x8*)(vbase + (size_t)(2 * vr) * C3 + vc);
    s16x8 vbv = *(const s16x8*)(vbase + (size_t)(2 * vr + 1) * C3 + vc);
    char* vd = (char*)&vbuf[0][0];
#pragma unroll
    for (int i = 0; i < 8; i++) {
      unsigned dw = (unsigned)(unsigned short)va[i] | ((unsigned)(unsigned short)vbv[i] << 16);
      *(unsigned*)(vd + (vc + i) * 128 + (((vr >> 2) ^ i) * 16) + (vr & 3) * 4) = dw;
    }
  }
  __syncthreads();

  for (int tile = 0; tile < SEQ / 64; ++tile) {
    const int cur = tile & 1;
    const bool pf = (tile + 1 < SEQ / 64);
    s16x8 va, vbv;
    if (pf) {  // T14: issue next-tile loads early
      const int kv1 = (tile + 1) * 64;
      char* kd = (char*)&kbuf[cur ^ 1][0];
      gll16(kbase + (size_t)(kv1 + krow) * C3 + ksrc * 8,      kd + t * 16);
      gll16(kbase + (size_t)(kv1 + 32 + krow) * C3 + ksrc * 8, kd + 4096 + t * 16);
      va  = *(const s16x8*)(vbase + (size_t)(kv1 + 2 * vr) * C3 + vc);
      vbv = *(const s16x8*)(vbase + (size_t)(kv1 + 2 * vr + 1) * C3 + vc);
    }
    // ---- swapped QK^T: St[kv][q], lane owns q-col (l&31) ----
    const char* kb = (const char*)&kbuf[cur][0];
    f32x16 st0, st1;
#pragma unroll
    for (int r = 0; r < 16; r++) { st0[r] = 0.f; st1[r] = 0.f; }
#pragma unroll
    for (int dk = 0; dk < 4; dk++) {
      int chk = ((2 * dk + hi) ^ (l & 7)) * 16;
      s16x8 kf0 = *(const s16x8*)(kb + (size_t)lq * 128 + chk);
      s16x8 kf1 = *(const s16x8*)(kb + (size_t)(32 + lq) * 128 + chk);
      st0 = __builtin_amdgcn_mfma_f32_32x32x16_bf16(kf0, qf[dk], st0, 0, 0, 0);
      st1 = __builtin_amdgcn_mfma_f32_32x32x16_bf16(kf1, qf[dk], st1, 0, 0, 0);
    }
    // ---- online softmax, lane-local + one xor-32 ----
    float mx[16];
#pragma unroll
    for (int r = 0; r < 16; r++) mx[r] = fmaxf(st0[r], st1[r]);
#pragma unroll
    for (int sd = 8; sd >= 1; sd >>= 1)
#pragma unroll
      for (int r = 0; r < sd; r++) mx[r] = fmaxf(mx[r], mx[r + sd]);
    float mxf = fmaxf(mx[0], __shfl_xor(mx[0], 32));
    if (__any(mxf > m + 8.0f)) {   // T13 defer-max, wave-uniform
      float mnew = fmaxf(m, mxf);
      float alpha = __expf(m - mnew);
      m = mnew;
      lsum *= alpha;
      int ai = __builtin_bit_cast(int, alpha);
#pragma unroll
      for (int r = 0; r < 16; r++) {
        int qr = (r & 3) + 8 * (r >> 2) + 4 * hi;
        float ar = __builtin_bit_cast(float, __builtin_amdgcn_ds_bpermute(qr * 4, ai));
        o0[r] *= ar; o1[r] *= ar;
      }
    }
#pragma unroll
    for (int r = 0; r < 16; r++) {
      st0[r] = __expf(st0[r] - m);
      st1[r] = __expf(st1[r] - m);
    }
    float sm[16];
#pragma unroll
    for (int r = 0; r < 16; r++) sm[r] = st0[r] + st1[r];
#pragma unroll
    for (int sd = 8; sd >= 1; sd >>= 1)
#pragma unroll
      for (int r = 0; r < sd; r++) sm[r] += sm[r + sd];
    lsum += sm[0] + __shfl_xor(sm[0], 32);
    // ---- P -> bf16 A-frags in-register, PV ----
    const char* vbp = (const char*)&vbuf[cur][0];
#pragma unroll
    for (int n = 0; n < 2; n++) {
#pragma unroll
      for (int ksl = 0; ksl < 2; ksl++) {
        const f32x16& stn = n ? st1 : st0;
        int rb = ksl * 8;
        unsigned x  = pk2(stn[rb + 0], stn[rb + 1]);
        unsigned y  = pk2(stn[rb + 2], stn[rb + 3]);
        unsigned x2 = pk2(stn[rb + 4], stn[rb + 5]);
        unsigned y2 = pk2(stn[rb + 6], stn[rb + 7]);
        unsigned sx  = (unsigned)__shfl_xor((int)x, 32);
        unsigned sy  = (unsigned)__shfl_xor((int)y, 32);
        unsigned sx2 = (unsigned)__shfl_xor((int)x2, 32);
        unsigned sy2 = (unsigned)__shfl_xor((int)y2, 32);
        u32x4 fr;
        fr.x = hi ? sx2 : x;
        fr.y = hi ? sy2 : y;
        fr.z = hi ? x2 : sx;
        fr.w = hi ? y2 : sy;
        s16x8 pa = __builtin_bit_cast(s16x8, fr);
        int ks = n * 2 + ksl;
        int chk = ((2 * ks + hi) ^ (l & 7)) * 16;
        s16x8 vf0 = *(const s16x8*)(vbp + (size_t)lq * 128 + chk);
        s16x8 vf1 = *(const s16x8*)(vbp + (size_t)(32 + lq) * 128 + chk);
        o0 = __builtin_amdgcn_mfma_f32_32x32x16_bf16(pa, vf0, o0, 0, 0, 0);
        o1 = __builtin_amdgcn_mfma_f32_32x32x16_bf16(pa, vf1, o1, 0, 0, 0);
      }
    }
    if (pf) {  // write-late V into next buffer
      char* vd = (char*)&vbuf[cur ^ 1][0];
#pragma unroll
      for (int i = 0; i < 8; i++) {
        unsigned dw = (unsigned)(unsigned short)va[i] | ((unsigned)(unsigned short)vbv[i] << 16);
        *(unsigned*)(vd + (vc + i) * 128 + (((vr >> 2) ^ i) * 16) + (vr & 3) * 4) = dw;
      }
    }
    __syncthreads();
  }
  // ---- epilogue: normalize (bpermute 1/lsum per O-row) and store ----
  float inv = 1.0f / lsum;
  int ii = __builtin_bit_cast(int, inv);
#pragma unroll
  for (int r = 0; r < 16; r++) {
    int qr = (r & 3) + 8 * (r >> 2) + 4 * hi;
    float ir = __builtin_bit_cast(float, __builtin_amdgcn_ds_bpermute(qr * 4, ii));
    size_t rowoff = (size_t)(b * SEQ + qr0 + qr) * DIM + h * DH;
    attno[rowoff + lq]      = __float2bfloat16(o0[r] * ir);
    attno[rowoff + 32 + lq] = __float2bfloat16(o1[r] * ir);
  }
}

extern "C" void kernel_launch(void* const* d_in, const int* in_sizes, int n_in,
                              void* d_out, int out_size, void* d_ws, size_t ws_size,
                              hipStream_t stream) {
  const float* x     = (const float*)d_in[0];
  const float* gamma = (const float*)d_in[1];
  const float* beta  = (const float*)d_in[2];
  const float* Wqkv  = (const float*)d_in[3];
  const float* Wout  = (const float*)d_in[4];
  const float* bout  = (const float*)d_in[5];

  __hip_bfloat16* xn     = (__hip_bfloat16*)d_ws;
  __hip_bfloat16* wqkv_t = xn + (size_t)ROWS * DIM;        // [3072][1024]
  __hip_bfloat16* wout_t = wqkv_t + (size_t)C3 * DIM;      // [1024][1024]
  __hip_bfloat16* qkv    = wout_t + (size_t)DIM * DIM;     // [4096][3072]
  __hip_bfloat16* attno  = qkv + (size_t)ROWS * C3;        // [4096][1024]

  ln_kernel<<<ROWS, 256, 0, stream>>>(x, gamma, beta, xn);
  transpose_cvt<<<dim3(C3 / 32, DIM / 32), 256, 0, stream>>>(Wqkv, wqkv_t, DIM, C3);
  transpose_cvt<<<dim3(DIM / 32, DIM / 32), 256, 0, stream>>>(Wout, wout_t, DIM, DIM);
  gemm_bt<0><<<dim3(C3 / 128, ROWS / 128), 256, 0, stream>>>(xn, wqkv_t, (void*)qkv, nullptr, ROWS, C3, DIM);
  attn_kernel<<<dim3(SEQ / 128, BATCH * HEADS), 256, 0, stream>>>(qkv, attno);
  gemm_bt<1><<<dim3(DIM / 128, ROWS / 128), 256, 0, stream>>>(attno, wout_t, d_out, bout, ROWS, DIM, DIM);
}